// Round 13
// baseline (66.264 us; speedup 1.0000x reference)
//
#include <hip/hip_runtime.h>
#include <hip/hip_fp16.h>

// ApproxConv2d via 256x256 LUT (approximate multiplier).
// out[b,o,y,x] = sum_{c,ky,kx} lut[ qx(b,c,y+ky-1,x+kx-1)*256 + qw(o,c,ky,kx) ] + bias[o]
// qx/qw = clip(rint(v*64), -128, 127) + 128; padding -> qx=128 -> lut row 128 = 0.
//
// v13: o-QUAD b64 gathers (v8-proven: 1.18M wave-gathers @18.3cyc = 84k
// cyc/CU, vs o-pair b32's 2.75M @9.5 = 102k) under v7's proven schedule
// (4 channels staged per iteration -> 16 iters, 32 barriers; v8's loss was
// its 64 barriers). T[quad][c][ky][qx] row = 24B = 3 taps x
// {h(o0)|h(o1), h(o2)|h(o3)}; one ds_read_b64 = 4 MACs (2 __hadd2).
// Block = (quad, b, image-quarter): 4 channel-parities x 64 threads, 4-px
// strips; per iter stage 73728B (18 gll16/thread); LDS 76.9KB -> 2 blocks/CU.
// fp16 partials -> f32 every 2 channels (proven, absmax 0.0625).

#define NT 256

__device__ __forceinline__ int quantize(float v) {
    // clip(rint(v*64), -128, 127) + 128; rintf = round-half-to-even = jnp.round
    int q = (int)rintf(v * 64.0f);
    q = q < -128 ? -128 : q;
    q = q > 127 ? 127 : q;
    return q + 128;
}

__device__ __forceinline__ void gll16(const void* g, void* l) {
    __builtin_amdgcn_global_load_lds(
        (const __attribute__((address_space(1))) unsigned int*)g,
        (__attribute__((address_space(3))) unsigned int*)l, 16, 0, 0);
}

// -------- build: T[quad][c][ky][qx] 24B o-quad rows (v8 layout, 1024 blk) ---
__global__ __launch_bounds__(NT, 2)
void build_T4(const float* __restrict__ w, const float* __restrict__ lut,
              unsigned int* __restrict__ T)
{
    __shared__ float band[4 * 257];          // 4 lut rows, +1 pad
    __shared__ unsigned char qw4[4][576];

    const int tid = threadIdx.x;
    const int quad = blockIdx.x >> 6;        // 0..15
    const int q0 = (blockIdx.x & 63) << 2;   // qx slice base (4 rows)

    for (int i = tid; i < 4 * 576; i += NT) {
        int oo = i / 576, idx = i - oo * 576;
        qw4[oo][idx] = (unsigned char)quantize(w[(quad * 4 + oo) * 576 + idx]);
    }
    for (int i = tid; i < 4 * 256; i += NT) {
        int r = i >> 8, c2 = i & 255;
        band[r * 257 + c2] = lut[(q0 + r) * 256 + c2];
    }
    __syncthreads();

    // 64c x 3ky x 4qx = 768 items; each writes one 24B row (3x uint2)
    for (int it = 0; it < 3; ++it) {
        int idx = it * NT + tid;
        int c = idx / 12;
        int rem = idx - c * 12;
        int ky = rem >> 2;
        int qxl = rem & 3;
        const float* brow = band + qxl * 257;
        const int wb = c * 9 + ky * 3;
        unsigned int* dst =
            T + (((size_t)(quad * 64 + c) * 3 + ky) * 256 + q0 + qxl) * 6;
        #pragma unroll
        for (int k = 0; k < 3; ++k) {
            unsigned int h0 = __half_as_ushort(__float2half(brow[qw4[0][wb + k]]));
            unsigned int h1 = __half_as_ushort(__float2half(brow[qw4[1][wb + k]]));
            unsigned int h2 = __half_as_ushort(__float2half(brow[qw4[2][wb + k]]));
            unsigned int h3 = __half_as_ushort(__float2half(brow[qw4[3][wb + k]]));
            *(uint2*)(dst + k * 2) = make_uint2(h0 | (h1 << 16), h2 | (h3 << 16));
        }
    }
}

// -------- main: block = (quad, b, quarter); 4 parities x 64 thr, 4-px -------
__global__ __launch_bounds__(NT, 2)
void approx_main(const float* __restrict__ x, const unsigned int* __restrict__ T,
                 const float* __restrict__ bias, float* __restrict__ out)
{
    __shared__ __align__(16) unsigned char Ts[73728];   // 4 channels' o-quad T
    __shared__ unsigned int plane[4][2][100];           // [parity][buf] 10r x 40B

    const int tid = threadIdx.x;
    const int bid = blockIdx.x;
    const int quad = bid & 15;               // XCD = bid%8
    const int g = bid >> 4;                  // 0..31
    const int b = g >> 2;
    const int qt = g & 3;                    // image quarter (8 output rows)

    const int parity = tid >> 6;             // channel parity (c mod 4)
    const int lt = tid & 63;
    const int yl = lt >> 3;                  // local row 0..7
    const int x0 = (lt & 7) << 2;            // 4-px strip base col
    const int yg = qt * 8 + yl;

    const char* Tg = (const char*)T + (size_t)quad * 1179648;  // 64*3*256*24
    const float* xb = x + (size_t)b * 65536;

    for (int i = tid; i < 800; i += NT) ((unsigned int*)plane)[i] = 0x80808080u;

    // halo duty: 64 threads per parity own 2 halo rows x 32 cols
    const int hr = lt >> 5;                  // 0 top, 1 bottom
    const int hcol = lt & 31;
    const int hgrow = qt * 8 + (hr ? 8 : -1);
    const int hvalid = (hgrow >= 0 && hgrow < 32);
    const int hpr = hr ? 9 : 0;

    // prologue: pixels + halo for c = parity
    float4 xv = *(const float4*)(xb + parity * 1024 + yg * 32 + x0);
    float xh = hvalid ? xb[parity * 1024 + hgrow * 32 + hcol] : 0.f;

    __syncthreads();   // plane init complete

    const __half2 z2 = __float2half2_rn(0.f);
    __half2 acc2[4][2];                      // [px][o-pair: {o0o1},{o2o3}]
    float a32[4][4];                         // [px][o]
    #pragma unroll
    for (int p2 = 0; p2 < 4; ++p2) {
        acc2[p2][0] = z2; acc2[p2][1] = z2;
        #pragma unroll
        for (int oo = 0; oo < 4; ++oo) a32[p2][oo] = 0.f;
    }

    for (int t = 0; t < 16; ++t) {
        const int buf = t & 1;
        // plane write for c = 4t+parity
        unsigned char* pb = (unsigned char*)plane[parity][buf];
        unsigned int pk = (unsigned int)quantize(xv.x) |
                          ((unsigned int)quantize(xv.y) << 8) |
                          ((unsigned int)quantize(xv.z) << 16) |
                          ((unsigned int)quantize(xv.w) << 24);
        *(unsigned int*)(pb + (yl + 1) * 40 + 4 + x0) = pk;
        if (hvalid) pb[hpr * 40 + 4 + hcol] = (unsigned char)quantize(xh);

        // stage 4 channels' o-quad T (73728B = 18 x 4096) for this t
        {
            const char* src = Tg + (size_t)t * 73728 + tid * 16;
            char* dst = (char*)Ts + tid * 16;
            #pragma unroll
            for (int k = 0; k < 18; ++k) gll16(src + k * 4096, dst + k * 4096);
        }
        // prefetch next iteration's pixels
        if (t < 15) {
            const int cn = 4 * (t + 1) + parity;
            xv = *(const float4*)(xb + cn * 1024 + yg * 32 + x0);
            if (hvalid) xh = xb[cn * 1024 + hgrow * 32 + hcol];
        }
        __syncthreads();   // gll drained; planes visible

        // compute channel c = 4t+parity
        const unsigned int* pl = plane[parity][buf];
        const char* Tc = (const char*)Ts + parity * 18432;
        #pragma unroll
        for (int ky = 0; ky < 3; ++ky) {
            const int prow = (yl + ky) * 10 + (x0 >> 2);
            uint2 ua = *(const uint2*)&pl[prow];     // cols x0-4..x0-1 | x0..x0+3
            unsigned int uc = pl[prow + 2];          // cols x0+4..x0+7
            int m0 = (int)(ua.x >> 24);
            int m1 = (int)(ua.y & 255u), m2 = (int)((ua.y >> 8) & 255u);
            int m3 = (int)((ua.y >> 16) & 255u), m4 = (int)(ua.y >> 24);
            int m5 = (int)(uc & 255u);
            const char* Tk = Tc + ky * 6144;
            // row m_j, tap k feeds px j-k (0<=j-k<=3); V.x={o0,o1} V.y={o2,o3}
            uint2 V;
            V = *(const uint2*)(Tk + m0 * 24);        // j0 k0 -> px0
            acc2[0][0] = __hadd2(acc2[0][0], *(__half2*)&V.x);
            acc2[0][1] = __hadd2(acc2[0][1], *(__half2*)&V.y);
            V = *(const uint2*)(Tk + m1 * 24);        // j1 k0 -> px1
            acc2[1][0] = __hadd2(acc2[1][0], *(__half2*)&V.x);
            acc2[1][1] = __hadd2(acc2[1][1], *(__half2*)&V.y);
            V = *(const uint2*)(Tk + m1 * 24 + 8);    // j1 k1 -> px0
            acc2[0][0] = __hadd2(acc2[0][0], *(__half2*)&V.x);
            acc2[0][1] = __hadd2(acc2[0][1], *(__half2*)&V.y);
            V = *(const uint2*)(Tk + m2 * 24);        // j2 k0 -> px2
            acc2[2][0] = __hadd2(acc2[2][0], *(__half2*)&V.x);
            acc2[2][1] = __hadd2(acc2[2][1], *(__half2*)&V.y);
            V = *(const uint2*)(Tk + m2 * 24 + 8);    // j2 k1 -> px1
            acc2[1][0] = __hadd2(acc2[1][0], *(__half2*)&V.x);
            acc2[1][1] = __hadd2(acc2[1][1], *(__half2*)&V.y);
            V = *(const uint2*)(Tk + m2 * 24 + 16);   // j2 k2 -> px0
            acc2[0][0] = __hadd2(acc2[0][0], *(__half2*)&V.x);
            acc2[0][1] = __hadd2(acc2[0][1], *(__half2*)&V.y);
            V = *(const uint2*)(Tk + m3 * 24);        // j3 k0 -> px3
            acc2[3][0] = __hadd2(acc2[3][0], *(__half2*)&V.x);
            acc2[3][1] = __hadd2(acc2[3][1], *(__half2*)&V.y);
            V = *(const uint2*)(Tk + m3 * 24 + 8);    // j3 k1 -> px2
            acc2[2][0] = __hadd2(acc2[2][0], *(__half2*)&V.x);
            acc2[2][1] = __hadd2(acc2[2][1], *(__half2*)&V.y);
            V = *(const uint2*)(Tk + m3 * 24 + 16);   // j3 k2 -> px1
            acc2[1][0] = __hadd2(acc2[1][0], *(__half2*)&V.x);
            acc2[1][1] = __hadd2(acc2[1][1], *(__half2*)&V.y);
            V = *(const uint2*)(Tk + m4 * 24 + 8);    // j4 k1 -> px3
            acc2[3][0] = __hadd2(acc2[3][0], *(__half2*)&V.x);
            acc2[3][1] = __hadd2(acc2[3][1], *(__half2*)&V.y);
            V = *(const uint2*)(Tk + m4 * 24 + 16);   // j4 k2 -> px2
            acc2[2][0] = __hadd2(acc2[2][0], *(__half2*)&V.x);
            acc2[2][1] = __hadd2(acc2[2][1], *(__half2*)&V.y);
            V = *(const uint2*)(Tk + m5 * 24 + 16);   // j5 k2 -> px3
            acc2[3][0] = __hadd2(acc2[3][0], *(__half2*)&V.x);
            acc2[3][1] = __hadd2(acc2[3][1], *(__half2*)&V.y);
        }
        // migrate fp16 partials to f32 every 2 channels (18-term chunks)
        if (t & 1) {
            #pragma unroll
            for (int p2 = 0; p2 < 4; ++p2) {
                a32[p2][0] += __low2float(acc2[p2][0]);
                a32[p2][1] += __high2float(acc2[p2][0]);
                a32[p2][2] += __low2float(acc2[p2][1]);
                a32[p2][3] += __high2float(acc2[p2][1]);
                acc2[p2][0] = z2; acc2[p2][1] = z2;
            }
        }
        __syncthreads();   // compute done before next stage overwrites Ts
    }

    // cross-parity reduce via Ts (12KB), then bias + store
    float* red = (float*)Ts;
    if (parity) {
        #pragma unroll
        for (int p2 = 0; p2 < 4; ++p2)
            #pragma unroll
            for (int oo = 0; oo < 4; ++oo)
                red[(parity - 1) * 1024 + lt * 16 + p2 * 4 + oo] = a32[p2][oo];
    }
    __syncthreads();
    if (!parity) {
        const int o0 = quad * 4;
        #pragma unroll
        for (int oo = 0; oo < 4; ++oo) {
            float bo = bias[o0 + oo];
            float4 r;
            r.x = a32[0][oo] + red[lt * 16 + oo]      + red[1024 + lt * 16 + oo]
                + red[2048 + lt * 16 + oo] + bo;
            r.y = a32[1][oo] + red[lt * 16 + 4 + oo]  + red[1024 + lt * 16 + 4 + oo]
                + red[2048 + lt * 16 + 4 + oo] + bo;
            r.z = a32[2][oo] + red[lt * 16 + 8 + oo]  + red[1024 + lt * 16 + 8 + oo]
                + red[2048 + lt * 16 + 8 + oo] + bo;
            r.w = a32[3][oo] + red[lt * 16 + 12 + oo] + red[1024 + lt * 16 + 12 + oo]
                + red[2048 + lt * 16 + 12 + oo] + bo;
            *(float4*)(out + ((size_t)b * 64 + o0 + oo) * 1024 + yg * 32 + x0) = r;
        }
    }
}

// NOTE on reduce indexing: parity p stores a32[p2][oo] at lt*16 + p2*4 + oo;
// parity 0 reads px p2's slot as lt*16 + p2*4 + oo (see r.x..r.w above).

// -------- fallback (proven v1, 98us): used if ws too small ------------------
#define BW1 61
__global__ __launch_bounds__(NT, 2)
void approxconv2d_v1(const float* __restrict__ x,
                     const float* __restrict__ w,
                     const float* __restrict__ bias,
                     const float* __restrict__ lut,
                     float* __restrict__ out)
{
    __shared__ float band[256 * BW1];
    __shared__ unsigned int plane[340];
    __shared__ unsigned char qwrow[576];
    __shared__ int s_min;

    const int tid = threadIdx.x;
    const int bid = blockIdx.x;
    const int b = bid >> 6;
    const int o = bid & 63;

    if (tid == 0) s_min = 255;
    for (int i = tid; i < 340; i += NT) plane[i] = 0x80808080u;
    __syncthreads();

    int lmin = 255;
    for (int i = tid; i < 576; i += NT) {
        int q = quantize(w[o * 576 + i]);
        qwrow[i] = (unsigned char)q;
        lmin = lmin < q ? lmin : q;
    }
    atomicMin(&s_min, lmin);
    __syncthreads();

    int cmin = s_min;
    if (cmin > 256 - BW1) cmin = 256 - BW1;

    for (int i = tid; i < 256 * BW1; i += NT) {
        int qx = i / BW1;
        int cc = i - qx * BW1;
        band[i] = lut[(qx << 8) + cmin + cc];
    }

    const int y  = tid >> 3;
    const int xq = tid & 7;
    const int x0 = xq << 2;

    float acc0 = 0.f, acc1 = 0.f, acc2 = 0.f, acc3 = 0.f;
    const float* xb = x + (size_t)b * 64 * 1024;
    unsigned char* pb = (unsigned char*)plane;

    for (int c = 0; c < 64; ++c) {
        __syncthreads();
        float4 xv = *(const float4*)(xb + c * 1024 + y * 32 + x0);
        int qa = quantize(xv.x), qb = quantize(xv.y);
        int qc = quantize(xv.z), qd = quantize(xv.w);
        int wbase = (y + 1) * 40 + x0 + 1;
        pb[wbase + 0] = (unsigned char)qa;
        pb[wbase + 1] = (unsigned char)qb;
        pb[wbase + 2] = (unsigned char)qc;
        pb[wbase + 3] = (unsigned char)qd;
        __syncthreads();

        const unsigned char* qwp = qwrow + c * 9;
        #pragma unroll
        for (int ky = 0; ky < 3; ++ky) {
            int ro = (y + ky) * 10 + xq;
            unsigned int r0 = plane[ro];
            unsigned int r1 = plane[ro + 1];
            int ee[6];
            ee[0] = (int)(r0 & 255u);
            ee[1] = (int)((r0 >> 8) & 255u);
            ee[2] = (int)((r0 >> 16) & 255u);
            ee[3] = (int)(r0 >> 24);
            ee[4] = (int)(r1 & 255u);
            ee[5] = (int)((r1 >> 8) & 255u);
            int pp[6];
            #pragma unroll
            for (int tt = 0; tt < 6; ++tt) pp[tt] = ee[tt] * BW1;
            #pragma unroll
            for (int kx = 0; kx < 3; ++kx) {
                int cq = (int)qwp[ky * 3 + kx];
                int cc = cq - cmin;
                if ((unsigned)cc < (unsigned)BW1) {
                    acc0 += band[pp[kx + 0] + cc];
                    acc1 += band[pp[kx + 1] + cc];
                    acc2 += band[pp[kx + 2] + cc];
                    acc3 += band[pp[kx + 3] + cc];
                } else {
                    acc0 += lut[(ee[kx + 0] << 8) + cq];
                    acc1 += lut[(ee[kx + 1] << 8) + cq];
                    acc2 += lut[(ee[kx + 2] << 8) + cq];
                    acc3 += lut[(ee[kx + 3] << 8) + cq];
                }
            }
        }
    }

    float bo = bias[o];
    float4 r;
    r.x = acc0 + bo; r.y = acc1 + bo; r.z = acc2 + bo; r.w = acc3 + bo;
    *(float4*)(out + (size_t)bid * 1024 + y * 32 + x0) = r;
}

extern "C" void kernel_launch(void* const* d_in, const int* in_sizes, int n_in,
                              void* d_out, int out_size, void* d_ws, size_t ws_size,
                              hipStream_t stream) {
    const float* x    = (const float*)d_in[0];
    const float* wgt  = (const float*)d_in[1];
    const float* bias = (const float*)d_in[2];
    const float* lut  = (const float*)d_in[3];
    float* out = (float*)d_out;

    const size_t T_BYTES = (size_t)16 * 64 * 3 * 256 * 24;   // 18,874,368
    if (ws_size >= T_BYTES) {
        hipLaunchKernelGGL(build_T4, dim3(1024), dim3(NT), 0, stream,
                           wgt, lut, (unsigned int*)d_ws);
        hipLaunchKernelGGL(approx_main, dim3(512), dim3(NT), 0, stream,
                           x, (const unsigned int*)d_ws, bias, out);
    } else {
        hipLaunchKernelGGL(approxconv2d_v1, dim3(512), dim3(NT), 0, stream,
                           x, wgt, bias, lut, out);
    }
}

// Round 14
// 53.856 us; speedup vs baseline: 1.2304x; 1.2304x over previous
//
#include <hip/hip_runtime.h>
#include <hip/hip_fp16.h>

// ApproxConv2d via 256x256 LUT (approximate multiplier).
// out[b,o,y,x] = sum_{c,ky,kx} lut[ qx(b,c,y+ky-1,x+kx-1)*256 + qw(o,c,ky,kx) ] + bias[o]
// qx/qw = clip(rint(v*64), -128, 127) + 128; padding -> qx=128 -> lut row 128 = 0.
//
// v14 = v12 verbatim (proven best, 53.1us total): v7's approx_main (~43.5us:
// b32 o-pair tap rows at 12B stride -> all-32-bank spread; 8-px strips;
// 4 channel-parities x 64 threads; 36864B staged per 2-barrier iteration;
// fp16 __hadd2 accumulate with f32 migration every 2 channels) + 1024-block
// build_T3 (~4.5us).
// Ladder evidence (13 rounds): gather width b32>b64>b128; occupancy 2/CU
// optimal; counted-vmcnt dbuf neutral; resident-T + atomics regress;
// 4-channels-per-stage optimal. Main kernel LDS pipe ~98% busy at the
// measured random-gather conflict floor -> practical roofline.

#define NT 256

__device__ __forceinline__ int quantize(float v) {
    // clip(rint(v*64), -128, 127) + 128; rintf = round-half-to-even = jnp.round
    int q = (int)rintf(v * 64.0f);
    q = q < -128 ? -128 : q;
    q = q > 127 ? 127 : q;
    return q + 128;
}

__device__ __forceinline__ void gll16(const void* g, void* l) {
    __builtin_amdgcn_global_load_lds(
        (const __attribute__((address_space(1))) unsigned int*)g,
        (__attribute__((address_space(3))) unsigned int*)l, 16, 0, 0);
}

// -------- build: T[pair][c][ky][qx] 12B tap-interleaved rows ----------------
// 1024 blocks = (pair, 8-qx-row slice).
__global__ __launch_bounds__(NT, 2)
void build_T3(const float* __restrict__ w, const float* __restrict__ lut,
              unsigned int* __restrict__ T)
{
    __shared__ float band[8 * 257];
    __shared__ unsigned char qw2[2][576];

    const int tid = threadIdx.x;
    const int pair = blockIdx.x >> 5;       // 0..31
    const int qq = (blockIdx.x & 31) << 3;  // qx slice base (8 rows)

    for (int i = tid; i < 1152; i += NT) {
        int os = i >= 576;
        int idx = i - os * 576;
        qw2[os][idx] = (unsigned char)quantize(w[(pair * 2 + os) * 576 + idx]);
    }
    for (int i = tid; i < 8 * 256; i += NT) {
        int r = i >> 8, c2 = i & 255;
        band[r * 257 + c2] = lut[(qq + r) * 256 + c2];
    }
    __syncthreads();

    // 64c x 3ky x 8qx = 1536 items
    for (int it = 0; it < 6; ++it) {
        int idx = it * NT + tid;
        int c = idx / 24;
        int rem = idx - c * 24;
        int ky = rem >> 3;
        int qxl = rem & 7;
        const float* brow = band + qxl * 257;
        const unsigned char* q0 = &qw2[0][c * 9 + ky * 3];
        const unsigned char* q1 = &qw2[1][c * 9 + ky * 3];
        unsigned int* dst =
            T + ((size_t)((pair * 64 + c) * 3 + ky) * 256 + qq + qxl) * 3;
        #pragma unroll
        for (int k = 0; k < 3; ++k) {
            unsigned int h0 = __half_as_ushort(__float2half(brow[q0[k]]));
            unsigned int h1 = __half_as_ushort(__float2half(brow[q1[k]]));
            dst[k] = h0 | (h1 << 16);
        }
    }
}

// -------- main: v7 verbatim. block = (b, pair, half); 4 parities x 64 thr ---
__global__ __launch_bounds__(NT, 2)
void approx_main(const float* __restrict__ x, const unsigned int* __restrict__ T,
                 const float* __restrict__ bias, float* __restrict__ out)
{
    __shared__ __align__(16) unsigned char Ts[36864];   // 4 channels x 9216B
    __shared__ unsigned int plane[4][2][180];           // [parity][buf] 18r x 40B

    const int tid = threadIdx.x;
    const int bid = blockIdx.x;
    const int pair = bid & 31;               // XCD = bid%8 = pair%8
    const int bh = bid >> 5;                 // 0..15
    const int b = bh >> 1;
    const int h = bh & 1;

    const int parity = tid >> 6;             // channel parity (c mod 4)
    const int lt = tid & 63;
    const int yl = lt >> 2;                  // local out row 0..15
    const int xs = lt & 3;
    const int x0 = xs << 3;                  // 8-px strip base col
    const int yg = (h << 4) + yl;

    const char* Tg = (const char*)T + (size_t)pair * 589824;  // 64*3*256*12
    const float* xb = x + (size_t)b * 65536;

    const int halo_g  = h ? 15 : 16;         // real input row staged as halo
    const int halo_pr = h ? 0  : 17;         // plane row it lands in

    for (int i = tid; i < 1440; i += NT) ((unsigned int*)plane)[i] = 0x80808080u;

    // prologue: prefetch c = parity pixels
    float4 xv0 = *(const float4*)(xb + parity * 1024 + yg * 32 + x0);
    float4 xv1 = *(const float4*)(xb + parity * 1024 + yg * 32 + x0 + 4);
    float xh = (lt < 32) ? xb[parity * 1024 + halo_g * 32 + lt] : 0.f;

    __syncthreads();   // plane init complete

    const __half2 z2 = __float2half2_rn(0.f);
    float a32[8], b32[8];
    __half2 acc2[8];
    #pragma unroll
    for (int k = 0; k < 8; ++k) { a32[k] = 0.f; b32[k] = 0.f; acc2[k] = z2; }

    for (int t = 0; t < 16; ++t) {
        const int buf = t & 1;
        // plane write (this parity's channel c = 4t+parity)
        unsigned char* pb = (unsigned char*)plane[parity][buf];
        unsigned int pk0 = (unsigned int)quantize(xv0.x) |
                           ((unsigned int)quantize(xv0.y) << 8) |
                           ((unsigned int)quantize(xv0.z) << 16) |
                           ((unsigned int)quantize(xv0.w) << 24);
        unsigned int pk1 = (unsigned int)quantize(xv1.x) |
                           ((unsigned int)quantize(xv1.y) << 8) |
                           ((unsigned int)quantize(xv1.z) << 16) |
                           ((unsigned int)quantize(xv1.w) << 24);
        *(unsigned int*)(pb + (yl + 1) * 40 + 4 + x0)     = pk0;
        *(unsigned int*)(pb + (yl + 1) * 40 + 4 + x0 + 4) = pk1;
        if (lt < 32) pb[halo_pr * 40 + 4 + lt] = (unsigned char)quantize(xh);

        // stage 4 channels' T (36864B) for this t
        {
            const char* src = Tg + t * 36864 + tid * 16;
            char* dst = (char*)Ts + tid * 16;
            #pragma unroll
            for (int k = 0; k < 9; ++k) gll16(src + k * 4096, dst + k * 4096);
        }
        // prefetch next channel's pixels
        if (t < 15) {
            const int c1 = 4 * (t + 1) + parity;
            xv0 = *(const float4*)(xb + c1 * 1024 + yg * 32 + x0);
            xv1 = *(const float4*)(xb + c1 * 1024 + yg * 32 + x0 + 4);
            if (lt < 32) xh = xb[c1 * 1024 + halo_g * 32 + lt];
        }
        __syncthreads();   // gll drained; planes visible

        // compute channel c = 4t+parity
        const unsigned int* pl = plane[parity][buf];
        const char* Tc = (const char*)Ts + parity * 9216;
        #pragma unroll
        for (int ky = 0; ky < 3; ++ky) {
            const int prow = (yl + ky) * 10 + (x0 >> 2);
            uint2 ua = *(const uint2*)&pl[prow];       // cols x0-4..x0-1 | x0..x0+3
            uint2 ub = *(const uint2*)&pl[prow + 2];   // cols x0+4..x0+7 | x0+8..
            int m[10];
            m[0] = (int)(ua.x >> 24);
            m[1] = (int)(ua.y & 255u);  m[2] = (int)((ua.y >> 8) & 255u);
            m[3] = (int)((ua.y >> 16) & 255u); m[4] = (int)(ua.y >> 24);
            m[5] = (int)(ub.x & 255u);  m[6] = (int)((ub.x >> 8) & 255u);
            m[7] = (int)((ub.x >> 16) & 255u); m[8] = (int)(ub.x >> 24);
            m[9] = (int)(ub.y & 255u);
            const char* Tk = Tc + ky * 3072;
            #pragma unroll
            for (int j = 0; j < 10; ++j) {
                const unsigned int* R = (const unsigned int*)(Tk + m[j] * 12);
                // w_k = half(o0 tap_k) | half(o1 tap_k)<<16; tap kx feeds px j-kx
                if (j <= 7) {
                    unsigned int w0 = R[0];
                    acc2[j] = __hadd2(acc2[j], *(const __half2*)&w0);
                }
                if (j >= 1 && j <= 8) {
                    unsigned int w1 = R[1];
                    acc2[j - 1] = __hadd2(acc2[j - 1], *(const __half2*)&w1);
                }
                if (j >= 2) {
                    unsigned int w2 = R[2];
                    acc2[j - 2] = __hadd2(acc2[j - 2], *(const __half2*)&w2);
                }
            }
        }
        // migrate fp16 partials to f32 every 2 channels (bounded rounding)
        if (t & 1) {
            #pragma unroll
            for (int k = 0; k < 8; ++k) {
                a32[k] += __low2float(acc2[k]);
                b32[k] += __high2float(acc2[k]);
                acc2[k] = z2;
            }
        }
        __syncthreads();   // compute done before next stage overwrites Ts
    }

    // cross-parity reduce: parities 1..3 dump, parity 0 sums + bias + store
    float* red = (float*)Ts;
    if (parity) {
        #pragma unroll
        for (int k = 0; k < 8; ++k) {
            red[(parity - 1) * 1024 + lt * 16 + k]     = a32[k];
            red[(parity - 1) * 1024 + lt * 16 + 8 + k] = b32[k];
        }
    }
    __syncthreads();
    if (!parity) {
        const int o0 = pair * 2;
        float bo0 = bias[o0], bo1 = bias[o0 + 1];
        float r0[8], r1[8];
        #pragma unroll
        for (int k = 0; k < 8; ++k) {
            r0[k] = a32[k] + red[lt * 16 + k] + red[1024 + lt * 16 + k]
                  + red[2048 + lt * 16 + k] + bo0;
            r1[k] = b32[k] + red[lt * 16 + 8 + k] + red[1024 + lt * 16 + 8 + k]
                  + red[2048 + lt * 16 + 8 + k] + bo1;
        }
        float* p0 = out + ((size_t)b * 64 + o0) * 1024 + yg * 32 + x0;
        *(float4*)(p0)     = make_float4(r0[0], r0[1], r0[2], r0[3]);
        *(float4*)(p0 + 4) = make_float4(r0[4], r0[5], r0[6], r0[7]);
        float* p1 = p0 + 1024;
        *(float4*)(p1)     = make_float4(r1[0], r1[1], r1[2], r1[3]);
        *(float4*)(p1 + 4) = make_float4(r1[4], r1[5], r1[6], r1[7]);
    }
}

// -------- fallback (proven v1, 98us): used if ws too small ------------------
#define BW1 61
__global__ __launch_bounds__(NT, 2)
void approxconv2d_v1(const float* __restrict__ x,
                     const float* __restrict__ w,
                     const float* __restrict__ bias,
                     const float* __restrict__ lut,
                     float* __restrict__ out)
{
    __shared__ float band[256 * BW1];
    __shared__ unsigned int plane[340];
    __shared__ unsigned char qwrow[576];
    __shared__ int s_min;

    const int tid = threadIdx.x;
    const int bid = blockIdx.x;
    const int b = bid >> 6;
    const int o = bid & 63;

    if (tid == 0) s_min = 255;
    for (int i = tid; i < 340; i += NT) plane[i] = 0x80808080u;
    __syncthreads();

    int lmin = 255;
    for (int i = tid; i < 576; i += NT) {
        int q = quantize(w[o * 576 + i]);
        qwrow[i] = (unsigned char)q;
        lmin = lmin < q ? lmin : q;
    }
    atomicMin(&s_min, lmin);
    __syncthreads();

    int cmin = s_min;
    if (cmin > 256 - BW1) cmin = 256 - BW1;

    for (int i = tid; i < 256 * BW1; i += NT) {
        int qx = i / BW1;
        int cc = i - qx * BW1;
        band[i] = lut[(qx << 8) + cmin + cc];
    }

    const int y  = tid >> 3;
    const int xq = tid & 7;
    const int x0 = xq << 2;

    float acc0 = 0.f, acc1 = 0.f, acc2 = 0.f, acc3 = 0.f;
    const float* xb = x + (size_t)b * 64 * 1024;
    unsigned char* pb = (unsigned char*)plane;

    for (int c = 0; c < 64; ++c) {
        __syncthreads();
        float4 xv = *(const float4*)(xb + c * 1024 + y * 32 + x0);
        int qa = quantize(xv.x), qb = quantize(xv.y);
        int qc = quantize(xv.z), qd = quantize(xv.w);
        int wbase = (y + 1) * 40 + x0 + 1;
        pb[wbase + 0] = (unsigned char)qa;
        pb[wbase + 1] = (unsigned char)qb;
        pb[wbase + 2] = (unsigned char)qc;
        pb[wbase + 3] = (unsigned char)qd;
        __syncthreads();

        const unsigned char* qwp = qwrow + c * 9;
        #pragma unroll
        for (int ky = 0; ky < 3; ++ky) {
            int ro = (y + ky) * 10 + xq;
            unsigned int r0 = plane[ro];
            unsigned int r1 = plane[ro + 1];
            int ee[6];
            ee[0] = (int)(r0 & 255u);
            ee[1] = (int)((r0 >> 8) & 255u);
            ee[2] = (int)((r0 >> 16) & 255u);
            ee[3] = (int)(r0 >> 24);
            ee[4] = (int)(r1 & 255u);
            ee[5] = (int)((r1 >> 8) & 255u);
            int pp[6];
            #pragma unroll
            for (int tt = 0; tt < 6; ++tt) pp[tt] = ee[tt] * BW1;
            #pragma unroll
            for (int kx = 0; kx < 3; ++kx) {
                int cq = (int)qwp[ky * 3 + kx];
                int cc = cq - cmin;
                if ((unsigned)cc < (unsigned)BW1) {
                    acc0 += band[pp[kx + 0] + cc];
                    acc1 += band[pp[kx + 1] + cc];
                    acc2 += band[pp[kx + 2] + cc];
                    acc3 += band[pp[kx + 3] + cc];
                } else {
                    acc0 += lut[(ee[kx + 0] << 8) + cq];
                    acc1 += lut[(ee[kx + 1] << 8) + cq];
                    acc2 += lut[(ee[kx + 2] << 8) + cq];
                    acc3 += lut[(ee[kx + 3] << 8) + cq];
                }
            }
        }
    }

    float bo = bias[o];
    float4 r;
    r.x = acc0 + bo; r.y = acc1 + bo; r.z = acc2 + bo; r.w = acc3 + bo;
    *(float4*)(out + (size_t)bid * 1024 + y * 32 + x0) = r;
}

extern "C" void kernel_launch(void* const* d_in, const int* in_sizes, int n_in,
                              void* d_out, int out_size, void* d_ws, size_t ws_size,
                              hipStream_t stream) {
    const float* x    = (const float*)d_in[0];
    const float* wgt  = (const float*)d_in[1];
    const float* bias = (const float*)d_in[2];
    const float* lut  = (const float*)d_in[3];
    float* out = (float*)d_out;

    const size_t T_BYTES = (size_t)32 * 64 * 3 * 256 * 12;   // 18,874,368
    if (ws_size >= T_BYTES) {
        hipLaunchKernelGGL(build_T3, dim3(1024), dim3(NT), 0, stream,
                           wgt, lut, (unsigned int*)d_ws);
        hipLaunchKernelGGL(approx_main, dim3(512), dim3(NT), 0, stream,
                           x, (const unsigned int*)d_ws, bias, out);
    } else {
        hipLaunchKernelGGL(approxconv2d_v1, dim3(512), dim3(NT), 0, stream,
                           x, wgt, bias, lut, out);
    }
}